// Round 2
// baseline (1342.461 us; speedup 1.0000x reference)
//
#include <hip/hip_runtime.h>
#include <hip/hip_bf16.h>

#define N_NODES 100000
#define N_EDGES 1600000
#define N_GRAPH 512
#define DIN 100
#define DOUT 200
#define HID 400

#define SPLIT 4            // blocks per graph in scatter2

// ---------------- init: deg=1 (self-loop), zeros ----------------
__global__ void init_kernel(float* deg, float* cnt, float* accg,
                            int* ehist, int* cursor) {
    int i = blockIdx.x * blockDim.x + threadIdx.x;
    if (i < N_NODES) deg[i] = 1.0f;
    if (i < N_GRAPH) {
        cnt[i] = 0.0f;
        if (ehist)  ehist[i] = 0;
        if (cursor) cursor[i] = 0;
    }
    if (i < N_GRAPH * DIN) accg[i] = 0.0f;
}

// ---------------- degree + per-graph edge histogram; cache ge ----------------
__global__ void deg_hist_kernel(const int* __restrict__ dst, const int* __restrict__ batch,
                                float* __restrict__ deg, int* __restrict__ ehist,
                                int* __restrict__ ge) {
    int e = blockIdx.x * blockDim.x + threadIdx.x;
    if (e >= N_EDGES) return;
    int t = dst[e];
    atomicAdd(&deg[t], 1.0f);
    int g = batch[t];
    ge[e] = g;
    atomicAdd(&ehist[g], 1);
}

// degree only (fallback)
__global__ void deg_only_kernel(const int* __restrict__ dst, float* __restrict__ deg) {
    int e = blockIdx.x * blockDim.x + threadIdx.x;
    if (e < N_EDGES) atomicAdd(&deg[dst[e]], 1.0f);
}

// ---------------- dinv = rsqrt(deg); per-graph node counts ----------------
__global__ void dinv_kernel(const float* __restrict__ deg, float* __restrict__ dinv,
                            const int* __restrict__ batch, float* __restrict__ cnt) {
    int i = blockIdx.x * blockDim.x + threadIdx.x;
    if (i < N_NODES) {
        float d = deg[i];
        dinv[i] = d > 0.0f ? rsqrtf(d) : 0.0f;
        atomicAdd(&cnt[batch[i]], 1.0f);
    }
}

__device__ __forceinline__ int lower_bound_dev(const int* a, int n, int v) {
    int lo = 0, hi = n;
    while (lo < hi) { int m = (lo + hi) >> 1; if (a[m] < v) lo = m + 1; else hi = m; }
    return lo;
}

// ---------------- scan: binstart = exclusive prefix(ehist); nodestart via search ----------------
__global__ void scan_kernel(const int* __restrict__ ehist, int* __restrict__ binstart,
                            const int* __restrict__ batch, int* __restrict__ nodestart) {
    __shared__ int tmp[N_GRAPH];
    int t = threadIdx.x;                      // 512 threads
    tmp[t] = ehist[t];
    __syncthreads();
    for (int off = 1; off < N_GRAPH; off <<= 1) {
        int v = (t >= off) ? tmp[t - off] : 0;
        __syncthreads();
        tmp[t] += v;
        __syncthreads();
    }
    binstart[t + 1] = tmp[t];
    if (t == 0) binstart[0] = 0;
    nodestart[t] = lower_bound_dev(batch, N_NODES, t);
    if (t == 0) nodestart[N_GRAPH] = N_NODES;
}

// ---------------- fill bins: (src, weight) per edge, grouped by g ----------------
__global__ void fill_kernel(const int* __restrict__ ei, const int* __restrict__ ge,
                            const float* __restrict__ dinv, const int* __restrict__ binstart,
                            int* __restrict__ cursor, int2* __restrict__ bin) {
    int e = blockIdx.x * blockDim.x + threadIdx.x;
    if (e >= N_EDGES) return;
    int s = ei[e];
    int t = ei[N_EDGES + e];
    int g = ge[e];
    float w = dinv[s] * dinv[t];
    int pos = atomicAdd(&cursor[g], 1);
    bin[binstart[g] + pos] = make_int2(s, __float_as_int(w));
}

// ---------------- scatter2: per-graph register accumulation ----------------
__global__ __launch_bounds__(256)
void scatter2_kernel(const float* __restrict__ x, const int2* __restrict__ bin,
                     const int* __restrict__ binstart, const int* __restrict__ nodestart,
                     const float* __restrict__ dinv, float* __restrict__ accg) {
    const int g = blockIdx.x / SPLIT;
    const int q = blockIdx.x % SPLIT;
    const int tid = threadIdx.x;
    const int lane = tid & 31;
    const int eslot = tid >> 5;            // 8 slots of 32 lanes
    const bool act = lane < 25;            // 25 float4 = 100 floats per row
    const float4* __restrict__ x4 = (const float4*)x;

    int b0 = binstart[g], b1 = binstart[g + 1];
    int bn = b1 - b0;
    int e0 = b0 + (int)(((long long)bn * q) / SPLIT);
    int e1 = b0 + (int)(((long long)bn * (q + 1)) / SPLIT);

    int n0g = nodestart[g], n1g = nodestart[g + 1];
    int nn = n1g - n0g;
    int n0 = n0g + (int)(((long long)nn * q) / SPLIT);
    int n1 = n0g + (int)(((long long)nn * (q + 1)) / SPLIT);

    float4 acc = make_float4(0.f, 0.f, 0.f, 0.f);

    // real edges: unroll-4 independent gathers
    int i = e0 + eslot;
    for (; i + 24 < e1; i += 32) {
        int2 p0 = bin[i];
        int2 p1 = bin[i + 8];
        int2 p2 = bin[i + 16];
        int2 p3 = bin[i + 24];
        if (act) {
            float4 v0 = x4[p0.x * 25 + lane];
            float4 v1 = x4[p1.x * 25 + lane];
            float4 v2 = x4[p2.x * 25 + lane];
            float4 v3 = x4[p3.x * 25 + lane];
            float w0 = __int_as_float(p0.y), w1 = __int_as_float(p1.y);
            float w2 = __int_as_float(p2.y), w3 = __int_as_float(p3.y);
            acc.x += w0 * v0.x; acc.y += w0 * v0.y; acc.z += w0 * v0.z; acc.w += w0 * v0.w;
            acc.x += w1 * v1.x; acc.y += w1 * v1.y; acc.z += w1 * v1.z; acc.w += w1 * v1.w;
            acc.x += w2 * v2.x; acc.y += w2 * v2.y; acc.z += w2 * v2.z; acc.w += w2 * v2.w;
            acc.x += w3 * v3.x; acc.y += w3 * v3.y; acc.z += w3 * v3.z; acc.w += w3 * v3.w;
        }
    }
    for (; i < e1; i += 8) {
        int2 p = bin[i];
        if (act) {
            float4 v = x4[p.x * 25 + lane];
            float w = __int_as_float(p.y);
            acc.x += w * v.x; acc.y += w * v.y; acc.z += w * v.z; acc.w += w * v.w;
        }
    }

    // self-loops: contiguous node range, weight dinv^2
    for (int n = n0 + eslot; n < n1; n += 8) {
        float dv = dinv[n];
        float w = dv * dv;
        if (act) {
            float4 v = x4[n * 25 + lane];
            acc.x += w * v.x; acc.y += w * v.y; acc.z += w * v.z; acc.w += w * v.w;
        }
    }

    // combine 8 eslots via LDS, then one atomic per d
    __shared__ float lacc[DIN];
    if (tid < DIN) lacc[tid] = 0.0f;
    __syncthreads();
    if (act) {
        atomicAdd(&lacc[4 * lane + 0], acc.x);
        atomicAdd(&lacc[4 * lane + 1], acc.y);
        atomicAdd(&lacc[4 * lane + 2], acc.z);
        atomicAdd(&lacc[4 * lane + 3], acc.w);
    }
    __syncthreads();
    if (tid < DIN) atomicAdd(&accg[g * DIN + tid], lacc[tid]);
}

// ---------------- fallback scatter (small-ws path, like round-1 kernel) ----------------
__global__ __launch_bounds__(256)
void scatter_fb_kernel(const float* __restrict__ x, const int* __restrict__ ei,
                       const int* __restrict__ batch, const float* __restrict__ dinv,
                       float* __restrict__ accg) {
    __shared__ float lacc[N_GRAPH * 25];
    const int tid = threadIdx.x;
    for (int i = tid; i < N_GRAPH * 25; i += 256) lacc[i] = 0.0f;
    __syncthreads();
    const int ET = N_EDGES + N_NODES;
    const int doff = blockIdx.y * 25;
    const int per = (ET + 191) / 192;
    const int e0 = blockIdx.x * per;
    const int e1 = (e0 + per < ET) ? (e0 + per) : ET;
    const int grp = tid >> 5, lane = tid & 31;
    const bool lact = lane < 25;
    for (int e = e0 + grp; e < e1; e += 8) {
        int s, t;
        if (e < N_EDGES) { s = ei[e]; t = ei[N_EDGES + e]; }
        else             { s = e - N_EDGES; t = s; }
        float w = dinv[s] * dinv[t];
        int g = batch[t];
        if (lact) atomicAdd(&lacc[g * 25 + lane], w * x[s * DIN + doff + lane]);
    }
    __syncthreads();
    for (int i = tid; i < N_GRAPH * 25; i += 256) {
        int g = i / 25, d = i - g * 25;
        atomicAdd(&accg[g * DIN + doff + d], lacc[i]);
    }
}

// ---------------- pooled[g][j] = cnt[g]*b[j] + sum_d accg[g][d]*W[d][j] ----------------
__global__ void pooled_kernel(const float* __restrict__ accg, const float* __restrict__ W,
                              const float* __restrict__ b, const float* __restrict__ cnt,
                              float* __restrict__ pooled) {
    int i = blockIdx.x * blockDim.x + threadIdx.x;
    if (i >= N_GRAPH * DOUT) return;
    int g = i / DOUT, j = i - g * DOUT;
    const float* ar = accg + g * DIN;
    float p = cnt[g] * b[j];
    #pragma unroll 4
    for (int d = 0; d < DIN; ++d) p += ar[d] * W[d * DOUT + j];
    pooled[i] = p;
}

// ---------------- dense (+ ReLU) ----------------
template<int K, int M, bool RELU>
__global__ void mlp_kernel(const float* __restrict__ in, const float* __restrict__ Wt,
                           const float* __restrict__ bias, float* __restrict__ out) {
    int i = blockIdx.x * blockDim.x + threadIdx.x;
    if (i >= N_GRAPH * M) return;
    int g = i / M, m = i - g * M;
    const float* ir = in + g * K;
    float p = bias[m];
    #pragma unroll 4
    for (int k = 0; k < K; ++k) p += ir[k] * Wt[k * M + m];
    out[i] = RELU ? fmaxf(p, 0.0f) : p;
}

// ---------------- head: logits + softmax ----------------
__global__ void head_kernel(const float* __restrict__ z2, const float* __restrict__ Wc,
                            const float* __restrict__ bc, float* __restrict__ out) {
    int g = blockIdx.x * blockDim.x + threadIdx.x;
    if (g >= N_GRAPH) return;
    const float* zr = z2 + g * HID;
    float a0 = bc[0], a1 = bc[1];
    #pragma unroll 4
    for (int k = 0; k < HID; ++k) {
        float z = zr[k];
        a0 += z * Wc[2 * k];
        a1 += z * Wc[2 * k + 1];
    }
    float m = fmaxf(a0, a1);
    float e0 = expf(a0 - m), e1 = expf(a1 - m);
    float s = e0 + e1;
    out[2 * g]     = e0 / s;
    out[2 * g + 1] = e1 / s;
}

extern "C" void kernel_launch(void* const* d_in, const int* in_sizes, int n_in,
                              void* d_out, int out_size, void* d_ws, size_t ws_size,
                              hipStream_t stream) {
    const float* x  = (const float*)d_in[0];
    const float* W  = (const float*)d_in[1];
    const float* b  = (const float*)d_in[2];
    const float* W1 = (const float*)d_in[3];
    const float* b1 = (const float*)d_in[4];
    const float* W2 = (const float*)d_in[5];
    const float* b2 = (const float*)d_in[6];
    const float* Wc = (const float*)d_in[7];
    const float* bc = (const float*)d_in[8];
    const int*   ei = (const int*)d_in[9];
    const int* batch = (const int*)d_in[10];
    float* out = (float*)d_out;

    // workspace layout: core arrays first (fallback uses only these)
    char* wsp = (char*)d_ws;
    float* deg    = (float*)wsp; wsp += sizeof(float) * N_NODES;
    float* dinv   = (float*)wsp; wsp += sizeof(float) * N_NODES;
    float* cnt    = (float*)wsp; wsp += sizeof(float) * N_GRAPH;
    float* accg   = (float*)wsp; wsp += sizeof(float) * N_GRAPH * DIN;
    float* pooled = (float*)wsp; wsp += sizeof(float) * N_GRAPH * DOUT;
    float* z1     = (float*)wsp; wsp += sizeof(float) * N_GRAPH * HID;
    float* z2     = (float*)wsp; wsp += sizeof(float) * N_GRAPH * HID;
    int* ehist     = (int*)wsp; wsp += sizeof(int) * N_GRAPH;
    int* cursor    = (int*)wsp; wsp += sizeof(int) * N_GRAPH;
    int* binstart  = (int*)wsp; wsp += sizeof(int) * (N_GRAPH + 1);
    int* nodestart = (int*)wsp; wsp += sizeof(int) * (N_GRAPH + 1);
    int* ge        = (int*)wsp; wsp += sizeof(int) * N_EDGES;
    int2* bin      = (int2*)wsp; wsp += sizeof(int2) * N_EDGES;
    size_t full_need = (size_t)(wsp - (char*)d_ws);
    bool fast = ws_size >= full_need;

    if (fast) {
        init_kernel<<<(N_NODES + 255) / 256, 256, 0, stream>>>(deg, cnt, accg, ehist, cursor);
        deg_hist_kernel<<<(N_EDGES + 255) / 256, 256, 0, stream>>>(ei + N_EDGES, batch, deg, ehist, ge);
        dinv_kernel<<<(N_NODES + 255) / 256, 256, 0, stream>>>(deg, dinv, batch, cnt);
        scan_kernel<<<1, N_GRAPH, 0, stream>>>(ehist, binstart, batch, nodestart);
        fill_kernel<<<(N_EDGES + 255) / 256, 256, 0, stream>>>(ei, ge, dinv, binstart, cursor, bin);
        scatter2_kernel<<<N_GRAPH * SPLIT, 256, 0, stream>>>(x, bin, binstart, nodestart, dinv, accg);
    } else {
        init_kernel<<<(N_NODES + 255) / 256, 256, 0, stream>>>(deg, cnt, accg, nullptr, nullptr);
        deg_only_kernel<<<(N_EDGES + 255) / 256, 256, 0, stream>>>(ei + N_EDGES, deg);
        dinv_kernel<<<(N_NODES + 255) / 256, 256, 0, stream>>>(deg, dinv, batch, cnt);
        scatter_fb_kernel<<<dim3(192, 4), 256, 0, stream>>>(x, ei, batch, dinv, accg);
    }

    pooled_kernel<<<(N_GRAPH * DOUT + 255) / 256, 256, 0, stream>>>(accg, W, b, cnt, pooled);
    mlp_kernel<DOUT, HID, true><<<(N_GRAPH * HID + 255) / 256, 256, 0, stream>>>(pooled, W1, b1, z1);
    mlp_kernel<HID,  HID, true><<<(N_GRAPH * HID + 255) / 256, 256, 0, stream>>>(z1, W2, b2, z2);
    head_kernel<<<(N_GRAPH + 255) / 256, 256, 0, stream>>>(z2, Wc, bc, out);
}

// Round 3
// 456.807 us; speedup vs baseline: 2.9388x; 2.9388x over previous
//
#include <hip/hip_runtime.h>
#include <hip/hip_bf16.h>

#define N_NODES 100000
#define N_EDGES 1600000
#define N_GRAPH 512
#define DIN 100
#define DOUT 200
#define HID 400

#define SPLIT 4              // blocks per graph in scatter2
#define SUBB 32              // sub-bins per graph (de-contend atomics)
#define NBIN (N_GRAPH * SUBB)   // 16384

// ---------------- init: zeros ----------------
__global__ void init_kernel(int* ideg, float* accg, int* hist2, int* cur2) {
    int i = blockIdx.x * blockDim.x + threadIdx.x;
    if (i < N_NODES) ideg[i] = 0;
    if (hist2 && i < NBIN) { hist2[i] = 0; cur2[i] = 0; }
    if (i < N_GRAPH * DIN) accg[i] = 0.0f;
}

// ---------------- degree + sub-binned per-graph histogram; cache ge ----------------
__global__ void deg_hist_kernel(const int* __restrict__ dst, const int* __restrict__ batch,
                                int* __restrict__ ideg, int* __restrict__ hist2,
                                int* __restrict__ ge) {
    int e = blockIdx.x * blockDim.x + threadIdx.x;
    if (e >= N_EDGES) return;
    int t = dst[e];
    atomicAdd(&ideg[t], 1);                       // 100K bins, ~16/addr: low contention
    int g = batch[t];
    ge[e] = g;
    atomicAdd(&hist2[g * SUBB + (e & (SUBB - 1))], 1);   // 16384 bins, ~98/addr
}

// degree only (fallback)
__global__ void deg_only_kernel(const int* __restrict__ dst, int* __restrict__ ideg) {
    int e = blockIdx.x * blockDim.x + threadIdx.x;
    if (e < N_EDGES) atomicAdd(&ideg[dst[e]], 1);
}

// ---------------- dinv = rsqrt(deg+1)  (self-loop included) ----------------
__global__ void dinv_kernel(const int* __restrict__ ideg, float* __restrict__ dinv) {
    int i = blockIdx.x * blockDim.x + threadIdx.x;
    if (i < N_NODES) dinv[i] = rsqrtf((float)(ideg[i] + 1));
}

// cnt via atomics (fallback only)
__global__ void cnt_kernel(const int* __restrict__ batch, float* __restrict__ cnt) {
    int i = blockIdx.x * blockDim.x + threadIdx.x;
    if (i < N_GRAPH) cnt[i] = 0.0f;
}
__global__ void cnt2_kernel(const int* __restrict__ batch, float* __restrict__ cnt) {
    int i = blockIdx.x * blockDim.x + threadIdx.x;
    if (i < N_NODES) atomicAdd(&cnt[batch[i]], 1.0f);
}

__device__ __forceinline__ int lower_bound_dev(const int* a, int n, int v) {
    int lo = 0, hi = n;
    while (lo < hi) { int m = (lo + hi) >> 1; if (a[m] < v) lo = m + 1; else hi = m; }
    return lo;
}

// ---------------- scan2: exclusive scan of hist2[16384] -> base2;
//                  nodestart binary searches; cnt from diffs; graph bin starts ----------------
__global__ __launch_bounds__(1024)
void scan2_kernel(const int* __restrict__ hist2, int* __restrict__ base2,
                  const int* __restrict__ batch, int* __restrict__ nodestart,
                  float* __restrict__ cnt, int* __restrict__ gbinstart) {
    __shared__ int tsum[1024];
    const int t = threadIdx.x;                 // 1024 threads
    const int base = t * 16;
    int vals[16];
    int s = 0;
    #pragma unroll
    for (int k = 0; k < 16; ++k) { int v = hist2[base + k]; vals[k] = s; s += v; }
    tsum[t] = s;
    __syncthreads();
    for (int off = 1; off < 1024; off <<= 1) {
        int v = (t >= off) ? tsum[t - off] : 0;
        __syncthreads();
        tsum[t] += v;
        __syncthreads();
    }
    int boff = (t > 0) ? tsum[t - 1] : 0;      // exclusive block offset
    #pragma unroll
    for (int k = 0; k < 16; ++k) base2[base + k] = boff + vals[k];

    if (t < N_GRAPH) nodestart[t] = lower_bound_dev(batch, N_NODES, t);
    if (t == 0) nodestart[N_GRAPH] = N_NODES;
    __syncthreads();
    if (t < N_GRAPH) {
        cnt[t] = (float)(nodestart[t + 1] - nodestart[t]);
        gbinstart[t] = base2[t * SUBB];
    }
    if (t == 0) gbinstart[N_GRAPH] = N_EDGES;
}

// ---------------- fill bins: (src, weight) per edge, grouped by graph ----------------
__global__ void fill_kernel(const int* __restrict__ ei, const int* __restrict__ ge,
                            const float* __restrict__ dinv, const int* __restrict__ base2,
                            int* __restrict__ cur2, int2* __restrict__ bin) {
    int e = blockIdx.x * blockDim.x + threadIdx.x;
    if (e >= N_EDGES) return;
    int s = ei[e];
    int t = ei[N_EDGES + e];
    int g = ge[e];
    float w = dinv[s] * dinv[t];
    int bidx = g * SUBB + (e & (SUBB - 1));
    int pos = base2[bidx] + atomicAdd(&cur2[bidx], 1);
    bin[pos] = make_int2(s, __float_as_int(w));
}

// ---------------- scatter2: per-graph register accumulation ----------------
__global__ __launch_bounds__(256)
void scatter2_kernel(const float* __restrict__ x, const int2* __restrict__ bin,
                     const int* __restrict__ gbinstart, const int* __restrict__ nodestart,
                     const float* __restrict__ dinv, float* __restrict__ accg) {
    const int g = blockIdx.x / SPLIT;
    const int q = blockIdx.x % SPLIT;
    const int tid = threadIdx.x;
    const int lane = tid & 31;
    const int eslot = tid >> 5;            // 8 slots of 32 lanes
    const bool act = lane < 25;            // 25 float4 = 100 floats per row
    const float4* __restrict__ x4 = (const float4*)x;

    int b0 = gbinstart[g], b1 = gbinstart[g + 1];
    int bn = b1 - b0;
    int e0 = b0 + (int)(((long long)bn * q) / SPLIT);
    int e1 = b0 + (int)(((long long)bn * (q + 1)) / SPLIT);

    int n0g = nodestart[g], n1g = nodestart[g + 1];
    int nn = n1g - n0g;
    int n0 = n0g + (int)(((long long)nn * q) / SPLIT);
    int n1 = n0g + (int)(((long long)nn * (q + 1)) / SPLIT);

    float4 acc = make_float4(0.f, 0.f, 0.f, 0.f);

    // real edges: unroll-4 independent gathers
    int i = e0 + eslot;
    for (; i + 24 < e1; i += 32) {
        int2 p0 = bin[i];
        int2 p1 = bin[i + 8];
        int2 p2 = bin[i + 16];
        int2 p3 = bin[i + 24];
        if (act) {
            float4 v0 = x4[p0.x * 25 + lane];
            float4 v1 = x4[p1.x * 25 + lane];
            float4 v2 = x4[p2.x * 25 + lane];
            float4 v3 = x4[p3.x * 25 + lane];
            float w0 = __int_as_float(p0.y), w1 = __int_as_float(p1.y);
            float w2 = __int_as_float(p2.y), w3 = __int_as_float(p3.y);
            acc.x += w0 * v0.x; acc.y += w0 * v0.y; acc.z += w0 * v0.z; acc.w += w0 * v0.w;
            acc.x += w1 * v1.x; acc.y += w1 * v1.y; acc.z += w1 * v1.z; acc.w += w1 * v1.w;
            acc.x += w2 * v2.x; acc.y += w2 * v2.y; acc.z += w2 * v2.z; acc.w += w2 * v2.w;
            acc.x += w3 * v3.x; acc.y += w3 * v3.y; acc.z += w3 * v3.z; acc.w += w3 * v3.w;
        }
    }
    for (; i < e1; i += 8) {
        int2 p = bin[i];
        if (act) {
            float4 v = x4[p.x * 25 + lane];
            float w = __int_as_float(p.y);
            acc.x += w * v.x; acc.y += w * v.y; acc.z += w * v.z; acc.w += w * v.w;
        }
    }

    // self-loops: contiguous node range, weight dinv^2
    for (int n = n0 + eslot; n < n1; n += 8) {
        float dv = dinv[n];
        float w = dv * dv;
        if (act) {
            float4 v = x4[n * 25 + lane];
            acc.x += w * v.x; acc.y += w * v.y; acc.z += w * v.z; acc.w += w * v.w;
        }
    }

    // combine 8 eslots via LDS, then one atomic per d
    __shared__ float lacc[DIN];
    if (tid < DIN) lacc[tid] = 0.0f;
    __syncthreads();
    if (act) {
        atomicAdd(&lacc[4 * lane + 0], acc.x);
        atomicAdd(&lacc[4 * lane + 1], acc.y);
        atomicAdd(&lacc[4 * lane + 2], acc.z);
        atomicAdd(&lacc[4 * lane + 3], acc.w);
    }
    __syncthreads();
    if (tid < DIN) atomicAdd(&accg[g * DIN + tid], lacc[tid]);
}

// ---------------- fallback scatter (small-ws path) ----------------
__global__ __launch_bounds__(256)
void scatter_fb_kernel(const float* __restrict__ x, const int* __restrict__ ei,
                       const int* __restrict__ batch, const float* __restrict__ dinv,
                       float* __restrict__ accg) {
    __shared__ float lacc[N_GRAPH * 25];
    const int tid = threadIdx.x;
    for (int i = tid; i < N_GRAPH * 25; i += 256) lacc[i] = 0.0f;
    __syncthreads();
    const int ET = N_EDGES + N_NODES;
    const int doff = blockIdx.y * 25;
    const int per = (ET + 191) / 192;
    const int e0 = blockIdx.x * per;
    const int e1 = (e0 + per < ET) ? (e0 + per) : ET;
    const int grp = tid >> 5, lane = tid & 31;
    const bool lact = lane < 25;
    for (int e = e0 + grp; e < e1; e += 8) {
        int s, t;
        if (e < N_EDGES) { s = ei[e]; t = ei[N_EDGES + e]; }
        else             { s = e - N_EDGES; t = s; }
        float w = dinv[s] * dinv[t];
        int g = batch[t];
        if (lact) atomicAdd(&lacc[g * 25 + lane], w * x[s * DIN + doff + lane]);
    }
    __syncthreads();
    for (int i = tid; i < N_GRAPH * 25; i += 256) {
        int g = i / 25, d = i - g * 25;
        atomicAdd(&accg[g * DIN + doff + d], lacc[i]);
    }
}

// ---------------- pooled[g][j] = cnt[g]*b[j] + sum_d accg[g][d]*W[d][j] ----------------
__global__ void pooled_kernel(const float* __restrict__ accg, const float* __restrict__ W,
                              const float* __restrict__ b, const float* __restrict__ cnt,
                              float* __restrict__ pooled) {
    int i = blockIdx.x * blockDim.x + threadIdx.x;
    if (i >= N_GRAPH * DOUT) return;
    int g = i / DOUT, j = i - g * DOUT;
    const float* ar = accg + g * DIN;
    float p = cnt[g] * b[j];
    #pragma unroll 4
    for (int d = 0; d < DIN; ++d) p += ar[d] * W[d * DOUT + j];
    pooled[i] = p;
}

// ---------------- dense (+ ReLU) ----------------
template<int K, int M, bool RELU>
__global__ void mlp_kernel(const float* __restrict__ in, const float* __restrict__ Wt,
                           const float* __restrict__ bias, float* __restrict__ out) {
    int i = blockIdx.x * blockDim.x + threadIdx.x;
    if (i >= N_GRAPH * M) return;
    int g = i / M, m = i - g * M;
    const float* ir = in + g * K;
    float p = bias[m];
    #pragma unroll 4
    for (int k = 0; k < K; ++k) p += ir[k] * Wt[k * M + m];
    out[i] = RELU ? fmaxf(p, 0.0f) : p;
}

// ---------------- head: logits + softmax ----------------
__global__ void head_kernel(const float* __restrict__ z2, const float* __restrict__ Wc,
                            const float* __restrict__ bc, float* __restrict__ out) {
    int g = blockIdx.x * blockDim.x + threadIdx.x;
    if (g >= N_GRAPH) return;
    const float* zr = z2 + g * HID;
    float a0 = bc[0], a1 = bc[1];
    #pragma unroll 4
    for (int k = 0; k < HID; ++k) {
        float z = zr[k];
        a0 += z * Wc[2 * k];
        a1 += z * Wc[2 * k + 1];
    }
    float m = fmaxf(a0, a1);
    float e0 = expf(a0 - m), e1 = expf(a1 - m);
    float s = e0 + e1;
    out[2 * g]     = e0 / s;
    out[2 * g + 1] = e1 / s;
}

extern "C" void kernel_launch(void* const* d_in, const int* in_sizes, int n_in,
                              void* d_out, int out_size, void* d_ws, size_t ws_size,
                              hipStream_t stream) {
    const float* x  = (const float*)d_in[0];
    const float* W  = (const float*)d_in[1];
    const float* b  = (const float*)d_in[2];
    const float* W1 = (const float*)d_in[3];
    const float* b1 = (const float*)d_in[4];
    const float* W2 = (const float*)d_in[5];
    const float* b2 = (const float*)d_in[6];
    const float* Wc = (const float*)d_in[7];
    const float* bc = (const float*)d_in[8];
    const int*   ei = (const int*)d_in[9];
    const int* batch = (const int*)d_in[10];
    float* out = (float*)d_out;

    // workspace layout: core arrays first (fallback uses only these)
    char* wsp = (char*)d_ws;
    int*   ideg   = (int*)wsp;   wsp += sizeof(int)   * N_NODES;
    float* dinv   = (float*)wsp; wsp += sizeof(float) * N_NODES;
    float* cnt    = (float*)wsp; wsp += sizeof(float) * N_GRAPH;
    float* accg   = (float*)wsp; wsp += sizeof(float) * N_GRAPH * DIN;
    float* pooled = (float*)wsp; wsp += sizeof(float) * N_GRAPH * DOUT;
    float* z1     = (float*)wsp; wsp += sizeof(float) * N_GRAPH * HID;
    float* z2     = (float*)wsp; wsp += sizeof(float) * N_GRAPH * HID;
    size_t core_need = (size_t)(wsp - (char*)d_ws);
    int* hist2     = (int*)wsp; wsp += sizeof(int) * NBIN;
    int* cur2      = (int*)wsp; wsp += sizeof(int) * NBIN;
    int* base2     = (int*)wsp; wsp += sizeof(int) * NBIN;
    int* gbinstart = (int*)wsp; wsp += sizeof(int) * (N_GRAPH + 1);
    int* nodestart = (int*)wsp; wsp += sizeof(int) * (N_GRAPH + 1);
    int* ge        = (int*)wsp; wsp += sizeof(int) * N_EDGES;
    int2* bin      = (int2*)wsp; wsp += sizeof(int2) * N_EDGES;
    size_t full_need = (size_t)(wsp - (char*)d_ws);
    bool fast = ws_size >= full_need;
    (void)core_need;

    if (fast) {
        init_kernel<<<(N_NODES + 255) / 256, 256, 0, stream>>>(ideg, accg, hist2, cur2);
        deg_hist_kernel<<<(N_EDGES + 255) / 256, 256, 0, stream>>>(ei + N_EDGES, batch, ideg, hist2, ge);
        dinv_kernel<<<(N_NODES + 255) / 256, 256, 0, stream>>>(ideg, dinv);
        scan2_kernel<<<1, 1024, 0, stream>>>(hist2, base2, batch, nodestart, cnt, gbinstart);
        fill_kernel<<<(N_EDGES + 255) / 256, 256, 0, stream>>>(ei, ge, dinv, base2, cur2, bin);
        scatter2_kernel<<<N_GRAPH * SPLIT, 256, 0, stream>>>(x, bin, gbinstart, nodestart, dinv, accg);
    } else {
        init_kernel<<<(N_NODES + 255) / 256, 256, 0, stream>>>(ideg, accg, nullptr, nullptr);
        cnt_kernel<<<(N_GRAPH + 255) / 256, 256, 0, stream>>>(batch, cnt);
        deg_only_kernel<<<(N_EDGES + 255) / 256, 256, 0, stream>>>(ei + N_EDGES, ideg);
        dinv_kernel<<<(N_NODES + 255) / 256, 256, 0, stream>>>(ideg, dinv);
        cnt2_kernel<<<(N_NODES + 255) / 256, 256, 0, stream>>>(batch, cnt);
        scatter_fb_kernel<<<dim3(192, 4), 256, 0, stream>>>(x, ei, batch, dinv, accg);
    }

    pooled_kernel<<<(N_GRAPH * DOUT + 255) / 256, 256, 0, stream>>>(accg, W, b, cnt, pooled);
    mlp_kernel<DOUT, HID, true><<<(N_GRAPH * HID + 255) / 256, 256, 0, stream>>>(pooled, W1, b1, z1);
    mlp_kernel<HID,  HID, true><<<(N_GRAPH * HID + 255) / 256, 256, 0, stream>>>(z1, W2, b2, z2);
    head_kernel<<<(N_GRAPH + 255) / 256, 256, 0, stream>>>(z2, Wc, bc, out);
}

// Round 4
// 265.440 us; speedup vs baseline: 5.0575x; 1.7209x over previous
//
#include <hip/hip_runtime.h>
#include <hip/hip_bf16.h>

#define N_NODES 100000
#define N_EDGES 1600000
#define N_GRAPH 512
#define DIN 100
#define DOUT 200
#define HID 400

#define SPLIT 4               // blocks per graph in scatter2
#define NBLK 512              // binning blocks (chunks)
#define EPB (N_EDGES / NBLK)  // 3125 exactly
#define DEGTILE 4096          // LDS histogram tile for deg_kernel

__device__ __forceinline__ int lower_bound_dev(const int* a, int n, int v) {
    int lo = 0, hi = n;
    while (lo < hi) { int m = (lo + hi) >> 1; if (a[m] < v) lo = m + 1; else hi = m; }
    return lo;
}

// ---------------- K2: per-block per-graph LDS histogram (no global atomics) ----------------
__global__ __launch_bounds__(256)
void hist_kernel(const int* __restrict__ dst, const int* __restrict__ batch,
                 int* __restrict__ blockcnt) {
    __shared__ int h[N_GRAPH];
    const int b = blockIdx.x, tid = threadIdx.x;
    h[tid] = 0; h[tid + 256] = 0;
    __syncthreads();
    const int e0 = b * EPB, e1 = e0 + EPB;
    for (int e = e0 + tid; e < e1; e += 256) {
        int t = dst[e];
        atomicAdd(&h[batch[t]], 1);          // LDS atomic
    }
    __syncthreads();
    blockcnt[b * N_GRAPH + tid] = h[tid];
    blockcnt[b * N_GRAPH + tid + 256] = h[tid + 256];
}

// ---------------- K3a: per-graph exclusive scan over blocks ----------------
__global__ __launch_bounds__(512)
void colscan_kernel(const int* __restrict__ blockcnt, int* __restrict__ base2,
                    int* __restrict__ total) {
    __shared__ int c[NBLK], d2[NBLK];
    const int g = blockIdx.x, t = threadIdx.x;
    int v = blockcnt[t * N_GRAPH + g];
    c[t] = v;
    __syncthreads();
    int* s = c; int* d = d2;
    for (int off = 1; off < NBLK; off <<= 1) {
        int x = s[t];
        if (t >= off) x += s[t - off];
        d[t] = x;
        __syncthreads();
        int* tmp = s; s = d; d = tmp;
    }
    base2[t * N_GRAPH + g] = s[t] - v;       // exclusive prefix within column
    if (t == NBLK - 1) total[g] = s[t];
}

// ---------------- K3b: scan graph totals -> gbase; nodestart; cnt ----------------
__global__ __launch_bounds__(512)
void gscan_kernel(const int* __restrict__ total, int* __restrict__ gbase,
                  const int* __restrict__ batch, int* __restrict__ nodestart,
                  float* __restrict__ cnt) {
    __shared__ int c[N_GRAPH], d2[N_GRAPH];
    const int t = threadIdx.x;
    int v = total[t];
    c[t] = v;
    __syncthreads();
    int* s = c; int* d = d2;
    for (int off = 1; off < N_GRAPH; off <<= 1) {
        int x = s[t];
        if (t >= off) x += s[t - off];
        d[t] = x;
        __syncthreads();
        int* tmp = s; s = d; d = tmp;
    }
    gbase[t] = s[t] - v;
    if (t == N_GRAPH - 1) gbase[N_GRAPH] = s[t];   // = N_EDGES
    nodestart[t] = lower_bound_dev(batch, N_NODES, t);
    if (t == 0) nodestart[N_GRAPH] = N_NODES;
    __syncthreads();
    cnt[t] = (float)(nodestart[t + 1] - nodestart[t]);
}

// ---------------- K4: fill bins (s,t) with LDS cursors (no global atomics) ----------------
__global__ __launch_bounds__(256)
void fill_kernel(const int* __restrict__ src, const int* __restrict__ dst,
                 const int* __restrict__ batch, const int* __restrict__ base2,
                 const int* __restrict__ gbase, int2* __restrict__ bin) {
    __shared__ int cur[N_GRAPH];
    const int b = blockIdx.x, tid = threadIdx.x;
    cur[tid]       = gbase[tid]       + base2[b * N_GRAPH + tid];
    cur[tid + 256] = gbase[tid + 256] + base2[b * N_GRAPH + tid + 256];
    __syncthreads();
    const int e0 = b * EPB, e1 = e0 + EPB;
    for (int e = e0 + tid; e < e1; e += 256) {
        int s = src[e], t = dst[e];
        int g = batch[t];
        int pos = atomicAdd(&cur[g], 1);      // LDS atomic
        bin[pos] = make_int2(s, t);
    }
}

// ---------------- K5: per-graph degree via LDS histogram -> dinv (no global atomics) ----------------
__global__ __launch_bounds__(256)
void deg_kernel(const int2* __restrict__ bin, const int* __restrict__ gbase,
                const int* __restrict__ nodestart, float* __restrict__ dinv) {
    __shared__ int h[DEGTILE];
    const int g = blockIdx.x, tid = threadIdx.x;
    const int n0 = nodestart[g], n1 = nodestart[g + 1], nn = n1 - n0;
    const int e0 = gbase[g], e1 = gbase[g + 1];
    for (int t0 = 0; t0 < nn; t0 += DEGTILE) {
        const int tn = min(DEGTILE, nn - t0);
        for (int r = tid; r < tn; r += 256) h[r] = 0;
        __syncthreads();
        for (int i = e0 + tid; i < e1; i += 256) {
            int r = bin[i].y - n0 - t0;
            if (r >= 0 && r < tn) atomicAdd(&h[r], 1);   // LDS atomic
        }
        __syncthreads();
        for (int r = tid; r < tn; r += 256)
            dinv[n0 + t0 + r] = rsqrtf((float)(h[r] + 1));   // +1 self-loop
        __syncthreads();
    }
}

// ---------------- K6: scatter2 — per-graph register accumulation, non-atomic partials ----------------
__global__ __launch_bounds__(256)
void scatter2_kernel(const float* __restrict__ x, const int2* __restrict__ bin,
                     const int* __restrict__ gbase, const int* __restrict__ nodestart,
                     const float* __restrict__ dinv, float* __restrict__ accp) {
    const int g = blockIdx.x / SPLIT;
    const int q = blockIdx.x % SPLIT;
    const int tid = threadIdx.x;
    const int lane = tid & 31;
    const int eslot = tid >> 5;            // 8 slots of 32 lanes
    const bool act = lane < 25;            // 25 float4 = 100 floats per row
    const int wsrc = tid & 32;             // shfl source lane within wave
    const float4* __restrict__ x4 = (const float4*)x;

    int b0 = gbase[g], b1 = gbase[g + 1];
    int bn = b1 - b0;
    int e0 = b0 + (int)(((long long)bn * q) / SPLIT);
    int e1 = b0 + (int)(((long long)bn * (q + 1)) / SPLIT);

    int n0g = nodestart[g], n1g = nodestart[g + 1];
    int nn = n1g - n0g;
    int n0 = n0g + (int)(((long long)nn * q) / SPLIT);
    int n1 = n0g + (int)(((long long)nn * (q + 1)) / SPLIT);

    float4 acc = make_float4(0.f, 0.f, 0.f, 0.f);

    // real edges: unroll-4 independent gathers; weight computed by lane 0/32, shfl-broadcast
    int i = e0 + eslot;
    for (; i + 24 < e1; i += 32) {
        int2 p0 = bin[i];
        int2 p1 = bin[i + 8];
        int2 p2 = bin[i + 16];
        int2 p3 = bin[i + 24];
        float w0 = 0.f, w1 = 0.f, w2 = 0.f, w3 = 0.f;
        if ((tid & 31) == 0) {
            w0 = dinv[p0.x] * dinv[p0.y];
            w1 = dinv[p1.x] * dinv[p1.y];
            w2 = dinv[p2.x] * dinv[p2.y];
            w3 = dinv[p3.x] * dinv[p3.y];
        }
        w0 = __shfl(w0, wsrc, 64);
        w1 = __shfl(w1, wsrc, 64);
        w2 = __shfl(w2, wsrc, 64);
        w3 = __shfl(w3, wsrc, 64);
        if (act) {
            float4 v0 = x4[p0.x * 25 + lane];
            float4 v1 = x4[p1.x * 25 + lane];
            float4 v2 = x4[p2.x * 25 + lane];
            float4 v3 = x4[p3.x * 25 + lane];
            acc.x += w0 * v0.x; acc.y += w0 * v0.y; acc.z += w0 * v0.z; acc.w += w0 * v0.w;
            acc.x += w1 * v1.x; acc.y += w1 * v1.y; acc.z += w1 * v1.z; acc.w += w1 * v1.w;
            acc.x += w2 * v2.x; acc.y += w2 * v2.y; acc.z += w2 * v2.z; acc.w += w2 * v2.w;
            acc.x += w3 * v3.x; acc.y += w3 * v3.y; acc.z += w3 * v3.z; acc.w += w3 * v3.w;
        }
    }
    for (; i < e1; i += 8) {
        int2 p = bin[i];
        float w = 0.f;
        if ((tid & 31) == 0) w = dinv[p.x] * dinv[p.y];
        w = __shfl(w, wsrc, 64);
        if (act) {
            float4 v = x4[p.x * 25 + lane];
            acc.x += w * v.x; acc.y += w * v.y; acc.z += w * v.z; acc.w += w * v.w;
        }
    }

    // self-loops: contiguous node range, weight dinv^2
    for (int n = n0 + eslot; n < n1; n += 8) {
        float dv = dinv[n];
        float w = dv * dv;
        if (act) {
            float4 v = x4[n * 25 + lane];
            acc.x += w * v.x; acc.y += w * v.y; acc.z += w * v.z; acc.w += w * v.w;
        }
    }

    // combine 8 eslots via LDS, then non-atomic partial write
    __shared__ float lacc[DIN];
    if (tid < DIN) lacc[tid] = 0.0f;
    __syncthreads();
    if (act) {
        atomicAdd(&lacc[4 * lane + 0], acc.x);
        atomicAdd(&lacc[4 * lane + 1], acc.y);
        atomicAdd(&lacc[4 * lane + 2], acc.z);
        atomicAdd(&lacc[4 * lane + 3], acc.w);
    }
    __syncthreads();
    if (tid < DIN) accp[blockIdx.x * DIN + tid] = lacc[tid];
}

// ---------------- fallback path kernels (small-ws) ----------------
__global__ void init_fb_kernel(int* ideg, float* accp, float* cnt) {
    int i = blockIdx.x * blockDim.x + threadIdx.x;
    if (i < N_NODES) ideg[i] = 0;
    if (i < N_GRAPH) cnt[i] = 0.0f;
    if (i < N_GRAPH * DIN) accp[i] = 0.0f;
}
__global__ void deg_only_kernel(const int* __restrict__ dst, int* __restrict__ ideg) {
    int e = blockIdx.x * blockDim.x + threadIdx.x;
    if (e < N_EDGES) atomicAdd(&ideg[dst[e]], 1);
}
__global__ void dinv_fb_kernel(const int* __restrict__ ideg, float* __restrict__ dinv,
                               const int* __restrict__ batch, float* __restrict__ cnt) {
    int i = blockIdx.x * blockDim.x + threadIdx.x;
    if (i < N_NODES) {
        dinv[i] = rsqrtf((float)(ideg[i] + 1));
        atomicAdd(&cnt[batch[i]], 1.0f);
    }
}
__global__ __launch_bounds__(256)
void scatter_fb_kernel(const float* __restrict__ x, const int* __restrict__ ei,
                       const int* __restrict__ batch, const float* __restrict__ dinv,
                       float* __restrict__ accp) {
    __shared__ float lacc[N_GRAPH * 25];
    const int tid = threadIdx.x;
    for (int i = tid; i < N_GRAPH * 25; i += 256) lacc[i] = 0.0f;
    __syncthreads();
    const int ET = N_EDGES + N_NODES;
    const int doff = blockIdx.y * 25;
    const int per = (ET + 191) / 192;
    const int e0 = blockIdx.x * per;
    const int e1 = (e0 + per < ET) ? (e0 + per) : ET;
    const int grp = tid >> 5, lane = tid & 31;
    const bool lact = lane < 25;
    for (int e = e0 + grp; e < e1; e += 8) {
        int s, t;
        if (e < N_EDGES) { s = ei[e]; t = ei[N_EDGES + e]; }
        else             { s = e - N_EDGES; t = s; }
        float w = dinv[s] * dinv[t];
        int g = batch[t];
        if (lact) atomicAdd(&lacc[g * 25 + lane], w * x[s * DIN + doff + lane]);
    }
    __syncthreads();
    for (int i = tid; i < N_GRAPH * 25; i += 256) {
        int g = i / 25, d = i - g * 25;
        atomicAdd(&accp[g * DIN + doff + d], lacc[i]);
    }
}

// ---------------- pooled[g][j] = cnt[g]*b[j] + sum_d (sum_q accp)[g][d] * W[d][j] ----------------
template<int NP>
__global__ void pooled_kernel(const float* __restrict__ accp, const float* __restrict__ W,
                              const float* __restrict__ b, const float* __restrict__ cnt,
                              float* __restrict__ pooled) {
    int i = blockIdx.x * blockDim.x + threadIdx.x;
    if (i >= N_GRAPH * DOUT) return;
    int g = i / DOUT, j = i - g * DOUT;
    float p = cnt[g] * b[j];
    #pragma unroll 2
    for (int d = 0; d < DIN; ++d) {
        float a = 0.f;
        #pragma unroll
        for (int q = 0; q < NP; ++q) a += accp[(g * NP + q) * DIN + d];
        p += a * W[d * DOUT + j];
    }
    pooled[i] = p;
}

// ---------------- dense (+ ReLU) ----------------
template<int K, int M, bool RELU>
__global__ void mlp_kernel(const float* __restrict__ in, const float* __restrict__ Wt,
                           const float* __restrict__ bias, float* __restrict__ out) {
    int i = blockIdx.x * blockDim.x + threadIdx.x;
    if (i >= N_GRAPH * M) return;
    int g = i / M, m = i - g * M;
    const float* ir = in + g * K;
    float p = bias[m];
    #pragma unroll 4
    for (int k = 0; k < K; ++k) p += ir[k] * Wt[k * M + m];
    out[i] = RELU ? fmaxf(p, 0.0f) : p;
}

// ---------------- head: logits + softmax ----------------
__global__ void head_kernel(const float* __restrict__ z2, const float* __restrict__ Wc,
                            const float* __restrict__ bc, float* __restrict__ out) {
    int g = blockIdx.x * blockDim.x + threadIdx.x;
    if (g >= N_GRAPH) return;
    const float* zr = z2 + g * HID;
    float a0 = bc[0], a1 = bc[1];
    #pragma unroll 4
    for (int k = 0; k < HID; ++k) {
        float z = zr[k];
        a0 += z * Wc[2 * k];
        a1 += z * Wc[2 * k + 1];
    }
    float m = fmaxf(a0, a1);
    float e0 = expf(a0 - m), e1 = expf(a1 - m);
    float s = e0 + e1;
    out[2 * g]     = e0 / s;
    out[2 * g + 1] = e1 / s;
}

extern "C" void kernel_launch(void* const* d_in, const int* in_sizes, int n_in,
                              void* d_out, int out_size, void* d_ws, size_t ws_size,
                              hipStream_t stream) {
    const float* x  = (const float*)d_in[0];
    const float* W  = (const float*)d_in[1];
    const float* b  = (const float*)d_in[2];
    const float* W1 = (const float*)d_in[3];
    const float* b1 = (const float*)d_in[4];
    const float* W2 = (const float*)d_in[5];
    const float* b2 = (const float*)d_in[6];
    const float* Wc = (const float*)d_in[7];
    const float* bc = (const float*)d_in[8];
    const int*   ei = (const int*)d_in[9];
    const int* batch = (const int*)d_in[10];
    float* out = (float*)d_out;
    const int* esrc = ei;
    const int* edst = ei + N_EDGES;

    // workspace layout: core arrays first (fallback uses only these)
    char* wsp = (char*)d_ws;
    float* dinv   = (float*)wsp; wsp += sizeof(float) * N_NODES;
    float* cnt    = (float*)wsp; wsp += sizeof(float) * N_GRAPH;
    float* accp   = (float*)wsp; wsp += sizeof(float) * N_GRAPH * SPLIT * DIN;
    float* pooled = (float*)wsp; wsp += sizeof(float) * N_GRAPH * DOUT;
    float* z1     = (float*)wsp; wsp += sizeof(float) * N_GRAPH * HID;
    float* z2     = (float*)wsp; wsp += sizeof(float) * N_GRAPH * HID;
    int*   ideg   = (int*)wsp;   wsp += sizeof(int) * N_NODES;      // fallback only
    size_t core_need = (size_t)(wsp - (char*)d_ws);
    int* blockcnt  = (int*)wsp; wsp += sizeof(int) * NBLK * N_GRAPH;
    int* base2     = (int*)wsp; wsp += sizeof(int) * NBLK * N_GRAPH;
    int* total     = (int*)wsp; wsp += sizeof(int) * N_GRAPH;
    int* gbase     = (int*)wsp; wsp += sizeof(int) * (N_GRAPH + 1);
    int* nodestart = (int*)wsp; wsp += sizeof(int) * (N_GRAPH + 1);
    int2* bin      = (int2*)wsp; wsp += sizeof(int2) * N_EDGES;
    size_t full_need = (size_t)(wsp - (char*)d_ws);
    bool fast = ws_size >= full_need;

    if (fast) {
        hist_kernel<<<NBLK, 256, 0, stream>>>(edst, batch, blockcnt);
        colscan_kernel<<<N_GRAPH, 512, 0, stream>>>(blockcnt, base2, total);
        gscan_kernel<<<1, 512, 0, stream>>>(total, gbase, batch, nodestart, cnt);
        fill_kernel<<<NBLK, 256, 0, stream>>>(esrc, edst, batch, base2, gbase, bin);
        deg_kernel<<<N_GRAPH, 256, 0, stream>>>(bin, gbase, nodestart, dinv);
        scatter2_kernel<<<N_GRAPH * SPLIT, 256, 0, stream>>>(x, bin, gbase, nodestart, dinv, accp);
        pooled_kernel<SPLIT><<<(N_GRAPH * DOUT + 255) / 256, 256, 0, stream>>>(accp, W, b, cnt, pooled);
    } else if (ws_size >= core_need) {
        init_fb_kernel<<<(N_NODES + 255) / 256, 256, 0, stream>>>(ideg, accp, cnt);
        deg_only_kernel<<<(N_EDGES + 255) / 256, 256, 0, stream>>>(edst, ideg);
        dinv_fb_kernel<<<(N_NODES + 255) / 256, 256, 0, stream>>>(ideg, dinv, batch, cnt);
        scatter_fb_kernel<<<dim3(192, 4), 256, 0, stream>>>(x, ei, batch, dinv, accp);
        pooled_kernel<1><<<(N_GRAPH * DOUT + 255) / 256, 256, 0, stream>>>(accp, W, b, cnt, pooled);
    }

    mlp_kernel<DOUT, HID, true><<<(N_GRAPH * HID + 255) / 256, 256, 0, stream>>>(pooled, W1, b1, z1);
    mlp_kernel<HID,  HID, true><<<(N_GRAPH * HID + 255) / 256, 256, 0, stream>>>(z1, W2, b2, z2);
    head_kernel<<<(N_GRAPH + 255) / 256, 256, 0, stream>>>(z2, Wc, bc, out);
}

// Round 5
// 236.120 us; speedup vs baseline: 5.6855x; 1.1242x over previous
//
#include <hip/hip_runtime.h>
#include <hip/hip_bf16.h>

#define N_NODES 100000
#define N_EDGES 1600000
#define N_GRAPH 512
#define DIN 100
#define DOUT 200
#define HID 400

#define SPLIT 4               // blocks per graph in scatter2
#define NBLK 512              // binning blocks (chunks)
#define EPB (N_EDGES / NBLK)  // 3125 exactly
#define DEGTILE 4096          // LDS histogram tile for deg_kernel
#define XB_WORDS (N_NODES * (DIN / 2))   // packed bf16 x: 50 words/row

__device__ __forceinline__ int lower_bound_dev(const int* a, int n, int v) {
    int lo = 0, hi = n;
    while (lo < hi) { int m = (lo + hi) >> 1; if (a[m] < v) lo = m + 1; else hi = m; }
    return lo;
}

__device__ __forceinline__ unsigned bfround(float f) {
    unsigned u = __float_as_uint(f);
    return (u + 0x7fffu + ((u >> 16) & 1u)) >> 16;   // RNE
}
__device__ __forceinline__ float bf_lo(unsigned u) { return __uint_as_float(u << 16); }
__device__ __forceinline__ float bf_hi(unsigned u) { return __uint_as_float(u & 0xffff0000u); }

// ---------------- K1: pack x to bf16 pairs (row = 50 uint32 = 200 B) ----------------
__global__ __launch_bounds__(256)
void pack_kernel(const float* __restrict__ x, unsigned* __restrict__ xb) {
    int i = blockIdx.x * blockDim.x + threadIdx.x;
    if (i < XB_WORDS) {
        float2 v = ((const float2*)x)[i];
        xb[i] = bfround(v.x) | (bfround(v.y) << 16);
    }
}

// ---------------- K2: per-block per-graph LDS histogram (no global atomics) ----------------
__global__ __launch_bounds__(256)
void hist_kernel(const int* __restrict__ dst, const int* __restrict__ batch,
                 int* __restrict__ blockcnt) {
    __shared__ int h[N_GRAPH];
    const int b = blockIdx.x, tid = threadIdx.x;
    h[tid] = 0; h[tid + 256] = 0;
    __syncthreads();
    const int e0 = b * EPB, e1 = e0 + EPB;
    for (int e = e0 + tid; e < e1; e += 256) {
        int t = dst[e];
        atomicAdd(&h[batch[t]], 1);          // LDS atomic
    }
    __syncthreads();
    blockcnt[b * N_GRAPH + tid] = h[tid];
    blockcnt[b * N_GRAPH + tid + 256] = h[tid + 256];
}

// ---------------- K3a: per-graph exclusive scan over blocks ----------------
__global__ __launch_bounds__(512)
void colscan_kernel(const int* __restrict__ blockcnt, int* __restrict__ base2,
                    int* __restrict__ total) {
    __shared__ int c[NBLK], d2[NBLK];
    const int g = blockIdx.x, t = threadIdx.x;
    int v = blockcnt[t * N_GRAPH + g];
    c[t] = v;
    __syncthreads();
    int* s = c; int* d = d2;
    for (int off = 1; off < NBLK; off <<= 1) {
        int x = s[t];
        if (t >= off) x += s[t - off];
        d[t] = x;
        __syncthreads();
        int* tmp = s; s = d; d = tmp;
    }
    base2[t * N_GRAPH + g] = s[t] - v;       // exclusive prefix within column
    if (t == NBLK - 1) total[g] = s[t];
}

// ---------------- K3b: scan graph totals -> gbase; nodestart; cnt ----------------
__global__ __launch_bounds__(512)
void gscan_kernel(const int* __restrict__ total, int* __restrict__ gbase,
                  const int* __restrict__ batch, int* __restrict__ nodestart,
                  float* __restrict__ cnt) {
    __shared__ int c[N_GRAPH], d2[N_GRAPH];
    const int t = threadIdx.x;
    int v = total[t];
    c[t] = v;
    __syncthreads();
    int* s = c; int* d = d2;
    for (int off = 1; off < N_GRAPH; off <<= 1) {
        int x = s[t];
        if (t >= off) x += s[t - off];
        d[t] = x;
        __syncthreads();
        int* tmp = s; s = d; d = tmp;
    }
    gbase[t] = s[t] - v;
    if (t == N_GRAPH - 1) gbase[N_GRAPH] = s[t];   // = N_EDGES
    nodestart[t] = lower_bound_dev(batch, N_NODES, t);
    if (t == 0) nodestart[N_GRAPH] = N_NODES;
    __syncthreads();
    cnt[t] = (float)(nodestart[t + 1] - nodestart[t]);
}

// ---------------- K4: fill bins (s,t) with LDS cursors (no global atomics) ----------------
__global__ __launch_bounds__(256)
void fill_kernel(const int* __restrict__ src, const int* __restrict__ dst,
                 const int* __restrict__ batch, const int* __restrict__ base2,
                 const int* __restrict__ gbase, int2* __restrict__ bin) {
    __shared__ int cur[N_GRAPH];
    const int b = blockIdx.x, tid = threadIdx.x;
    cur[tid]       = gbase[tid]       + base2[b * N_GRAPH + tid];
    cur[tid + 256] = gbase[tid + 256] + base2[b * N_GRAPH + tid + 256];
    __syncthreads();
    const int e0 = b * EPB, e1 = e0 + EPB;
    for (int e = e0 + tid; e < e1; e += 256) {
        int s = src[e], t = dst[e];
        int g = batch[t];
        int pos = atomicAdd(&cur[g], 1);      // LDS atomic
        bin[pos] = make_int2(s, t);
    }
}

// ---------------- K5: per-graph degree via LDS histogram -> dinv ----------------
__global__ __launch_bounds__(256)
void deg_kernel(const int2* __restrict__ bin, const int* __restrict__ gbase,
                const int* __restrict__ nodestart, float* __restrict__ dinv) {
    __shared__ int h[DEGTILE];
    const int g = blockIdx.x, tid = threadIdx.x;
    const int n0 = nodestart[g], n1 = nodestart[g + 1], nn = n1 - n0;
    const int e0 = gbase[g], e1 = gbase[g + 1];
    for (int t0 = 0; t0 < nn; t0 += DEGTILE) {
        const int tn = min(DEGTILE, nn - t0);
        for (int r = tid; r < tn; r += 256) h[r] = 0;
        __syncthreads();
        for (int i = e0 + tid; i < e1; i += 256) {
            int r = bin[i].y - n0 - t0;
            if (r >= 0 && r < tn) atomicAdd(&h[r], 1);   // LDS atomic
        }
        __syncthreads();
        for (int r = tid; r < tn; r += 256)
            dinv[n0 + t0 + r] = rsqrtf((float)(h[r] + 1));   // +1 self-loop
        __syncthreads();
    }
}

// ---------------- K6: scatter2 — per-graph register accumulation ----------------
// BF=1: gather packed-bf16 rows (200 B); BF=0: fp32 rows (400 B)
template<int BF>
__global__ __launch_bounds__(256)
void scatter2_kernel(const float* __restrict__ x, const uint2* __restrict__ xb,
                     const int2* __restrict__ bin,
                     const int* __restrict__ gbase, const int* __restrict__ nodestart,
                     const float* __restrict__ dinv, float* __restrict__ accp) {
    const int g = blockIdx.x / SPLIT;
    const int q = blockIdx.x % SPLIT;
    const int tid = threadIdx.x;
    const int lane = tid & 31;
    const int eslot = tid >> 5;            // 8 slots of 32 lanes
    const bool act = lane < 25;            // 25 x {8B bf16 | 16B f32} per row
    const int wsrc = tid & 32;             // shfl source lane within wave
    const float4* __restrict__ x4 = (const float4*)x;

    int b0 = gbase[g], b1 = gbase[g + 1];
    int bn = b1 - b0;
    int e0 = b0 + (int)(((long long)bn * q) / SPLIT);
    int e1 = b0 + (int)(((long long)bn * (q + 1)) / SPLIT);

    int n0g = nodestart[g], n1g = nodestart[g + 1];
    int nn = n1g - n0g;
    int n0 = n0g + (int)(((long long)nn * q) / SPLIT);
    int n1 = n0g + (int)(((long long)nn * (q + 1)) / SPLIT);

    float4 acc = make_float4(0.f, 0.f, 0.f, 0.f);

    // real edges: unroll-4 independent gathers; weight by lane 0/32, shfl-broadcast
    int i = e0 + eslot;
    for (; i + 24 < e1; i += 32) {
        int2 p0 = bin[i];
        int2 p1 = bin[i + 8];
        int2 p2 = bin[i + 16];
        int2 p3 = bin[i + 24];
        float w0 = 0.f, w1 = 0.f, w2 = 0.f, w3 = 0.f;
        if ((tid & 31) == 0) {
            w0 = dinv[p0.x] * dinv[p0.y];
            w1 = dinv[p1.x] * dinv[p1.y];
            w2 = dinv[p2.x] * dinv[p2.y];
            w3 = dinv[p3.x] * dinv[p3.y];
        }
        w0 = __shfl(w0, wsrc, 64);
        w1 = __shfl(w1, wsrc, 64);
        w2 = __shfl(w2, wsrc, 64);
        w3 = __shfl(w3, wsrc, 64);
        if (act) {
            if (BF) {
                uint2 u0 = xb[p0.x * 25 + lane];
                uint2 u1 = xb[p1.x * 25 + lane];
                uint2 u2 = xb[p2.x * 25 + lane];
                uint2 u3 = xb[p3.x * 25 + lane];
                acc.x += w0 * bf_lo(u0.x); acc.y += w0 * bf_hi(u0.x);
                acc.z += w0 * bf_lo(u0.y); acc.w += w0 * bf_hi(u0.y);
                acc.x += w1 * bf_lo(u1.x); acc.y += w1 * bf_hi(u1.x);
                acc.z += w1 * bf_lo(u1.y); acc.w += w1 * bf_hi(u1.y);
                acc.x += w2 * bf_lo(u2.x); acc.y += w2 * bf_hi(u2.x);
                acc.z += w2 * bf_lo(u2.y); acc.w += w2 * bf_hi(u2.y);
                acc.x += w3 * bf_lo(u3.x); acc.y += w3 * bf_hi(u3.x);
                acc.z += w3 * bf_lo(u3.y); acc.w += w3 * bf_hi(u3.y);
            } else {
                float4 v0 = x4[p0.x * 25 + lane];
                float4 v1 = x4[p1.x * 25 + lane];
                float4 v2 = x4[p2.x * 25 + lane];
                float4 v3 = x4[p3.x * 25 + lane];
                acc.x += w0 * v0.x; acc.y += w0 * v0.y; acc.z += w0 * v0.z; acc.w += w0 * v0.w;
                acc.x += w1 * v1.x; acc.y += w1 * v1.y; acc.z += w1 * v1.z; acc.w += w1 * v1.w;
                acc.x += w2 * v2.x; acc.y += w2 * v2.y; acc.z += w2 * v2.z; acc.w += w2 * v2.w;
                acc.x += w3 * v3.x; acc.y += w3 * v3.y; acc.z += w3 * v3.z; acc.w += w3 * v3.w;
            }
        }
    }
    for (; i < e1; i += 8) {
        int2 p = bin[i];
        float w = 0.f;
        if ((tid & 31) == 0) w = dinv[p.x] * dinv[p.y];
        w = __shfl(w, wsrc, 64);
        if (act) {
            if (BF) {
                uint2 u = xb[p.x * 25 + lane];
                acc.x += w * bf_lo(u.x); acc.y += w * bf_hi(u.x);
                acc.z += w * bf_lo(u.y); acc.w += w * bf_hi(u.y);
            } else {
                float4 v = x4[p.x * 25 + lane];
                acc.x += w * v.x; acc.y += w * v.y; acc.z += w * v.z; acc.w += w * v.w;
            }
        }
    }

    // self-loops: contiguous node range, weight dinv^2
    for (int n = n0 + eslot; n < n1; n += 8) {
        float dv = dinv[n];
        float w = dv * dv;
        if (act) {
            if (BF) {
                uint2 u = xb[n * 25 + lane];
                acc.x += w * bf_lo(u.x); acc.y += w * bf_hi(u.x);
                acc.z += w * bf_lo(u.y); acc.w += w * bf_hi(u.y);
            } else {
                float4 v = x4[n * 25 + lane];
                acc.x += w * v.x; acc.y += w * v.y; acc.z += w * v.z; acc.w += w * v.w;
            }
        }
    }

    // combine 8 eslots via LDS, then non-atomic partial write
    __shared__ float lacc[DIN];
    if (tid < DIN) lacc[tid] = 0.0f;
    __syncthreads();
    if (act) {
        atomicAdd(&lacc[4 * lane + 0], acc.x);
        atomicAdd(&lacc[4 * lane + 1], acc.y);
        atomicAdd(&lacc[4 * lane + 2], acc.z);
        atomicAdd(&lacc[4 * lane + 3], acc.w);
    }
    __syncthreads();
    if (tid < DIN) accp[blockIdx.x * DIN + tid] = lacc[tid];
}

// ---------------- fallback path kernels (small-ws) ----------------
__global__ void init_fb_kernel(int* ideg, float* accp, float* cnt) {
    int i = blockIdx.x * blockDim.x + threadIdx.x;
    if (i < N_NODES) ideg[i] = 0;
    if (i < N_GRAPH) cnt[i] = 0.0f;
    if (i < N_GRAPH * DIN) accp[i] = 0.0f;
}
__global__ void deg_only_kernel(const int* __restrict__ dst, int* __restrict__ ideg) {
    int e = blockIdx.x * blockDim.x + threadIdx.x;
    if (e < N_EDGES) atomicAdd(&ideg[dst[e]], 1);
}
__global__ void dinv_fb_kernel(const int* __restrict__ ideg, float* __restrict__ dinv,
                               const int* __restrict__ batch, float* __restrict__ cnt) {
    int i = blockIdx.x * blockDim.x + threadIdx.x;
    if (i < N_NODES) {
        dinv[i] = rsqrtf((float)(ideg[i] + 1));
        atomicAdd(&cnt[batch[i]], 1.0f);
    }
}
__global__ __launch_bounds__(256)
void scatter_fb_kernel(const float* __restrict__ x, const int* __restrict__ ei,
                       const int* __restrict__ batch, const float* __restrict__ dinv,
                       float* __restrict__ accp) {
    __shared__ float lacc[N_GRAPH * 25];
    const int tid = threadIdx.x;
    for (int i = tid; i < N_GRAPH * 25; i += 256) lacc[i] = 0.0f;
    __syncthreads();
    const int ET = N_EDGES + N_NODES;
    const int doff = blockIdx.y * 25;
    const int per = (ET + 191) / 192;
    const int e0 = blockIdx.x * per;
    const int e1 = (e0 + per < ET) ? (e0 + per) : ET;
    const int grp = tid >> 5, lane = tid & 31;
    const bool lact = lane < 25;
    for (int e = e0 + grp; e < e1; e += 8) {
        int s, t;
        if (e < N_EDGES) { s = ei[e]; t = ei[N_EDGES + e]; }
        else             { s = e - N_EDGES; t = s; }
        float w = dinv[s] * dinv[t];
        int g = batch[t];
        if (lact) atomicAdd(&lacc[g * 25 + lane], w * x[s * DIN + doff + lane]);
    }
    __syncthreads();
    for (int i = tid; i < N_GRAPH * 25; i += 256) {
        int g = i / 25, d = i - g * 25;
        atomicAdd(&accp[g * DIN + doff + d], lacc[i]);
    }
}

// ---------------- pooled[g][j] = cnt[g]*b[j] + sum_d (sum_q accp)[g][d] * W[d][j] ----------------
template<int NP>
__global__ void pooled_kernel(const float* __restrict__ accp, const float* __restrict__ W,
                              const float* __restrict__ b, const float* __restrict__ cnt,
                              float* __restrict__ pooled) {
    int i = blockIdx.x * blockDim.x + threadIdx.x;
    if (i >= N_GRAPH * DOUT) return;
    int g = i / DOUT, j = i - g * DOUT;
    float p = cnt[g] * b[j];
    #pragma unroll 2
    for (int d = 0; d < DIN; ++d) {
        float a = 0.f;
        #pragma unroll
        for (int q = 0; q < NP; ++q) a += accp[(g * NP + q) * DIN + d];
        p += a * W[d * DOUT + j];
    }
    pooled[i] = p;
}

// ---------------- dense (+ ReLU) ----------------
template<int K, int M, bool RELU>
__global__ void mlp_kernel(const float* __restrict__ in, const float* __restrict__ Wt,
                           const float* __restrict__ bias, float* __restrict__ out) {
    int i = blockIdx.x * blockDim.x + threadIdx.x;
    if (i >= N_GRAPH * M) return;
    int g = i / M, m = i - g * M;
    const float* ir = in + g * K;
    float p = bias[m];
    #pragma unroll 4
    for (int k = 0; k < K; ++k) p += ir[k] * Wt[k * M + m];
    out[i] = RELU ? fmaxf(p, 0.0f) : p;
}

// ---------------- head: logits + softmax ----------------
__global__ void head_kernel(const float* __restrict__ z2, const float* __restrict__ Wc,
                            const float* __restrict__ bc, float* __restrict__ out) {
    int g = blockIdx.x * blockDim.x + threadIdx.x;
    if (g >= N_GRAPH) return;
    const float* zr = z2 + g * HID;
    float a0 = bc[0], a1 = bc[1];
    #pragma unroll 4
    for (int k = 0; k < HID; ++k) {
        float z = zr[k];
        a0 += z * Wc[2 * k];
        a1 += z * Wc[2 * k + 1];
    }
    float m = fmaxf(a0, a1);
    float e0 = expf(a0 - m), e1 = expf(a1 - m);
    float s = e0 + e1;
    out[2 * g]     = e0 / s;
    out[2 * g + 1] = e1 / s;
}

extern "C" void kernel_launch(void* const* d_in, const int* in_sizes, int n_in,
                              void* d_out, int out_size, void* d_ws, size_t ws_size,
                              hipStream_t stream) {
    const float* x  = (const float*)d_in[0];
    const float* W  = (const float*)d_in[1];
    const float* b  = (const float*)d_in[2];
    const float* W1 = (const float*)d_in[3];
    const float* b1 = (const float*)d_in[4];
    const float* W2 = (const float*)d_in[5];
    const float* b2 = (const float*)d_in[6];
    const float* Wc = (const float*)d_in[7];
    const float* bc = (const float*)d_in[8];
    const int*   ei = (const int*)d_in[9];
    const int* batch = (const int*)d_in[10];
    float* out = (float*)d_out;
    const int* esrc = ei;
    const int* edst = ei + N_EDGES;

    // workspace layout: core arrays first (fallback uses only these)
    char* wsp = (char*)d_ws;
    float* dinv   = (float*)wsp; wsp += sizeof(float) * N_NODES;
    float* cnt    = (float*)wsp; wsp += sizeof(float) * N_GRAPH;
    float* accp   = (float*)wsp; wsp += sizeof(float) * N_GRAPH * SPLIT * DIN;
    float* pooled = (float*)wsp; wsp += sizeof(float) * N_GRAPH * DOUT;
    float* z1     = (float*)wsp; wsp += sizeof(float) * N_GRAPH * HID;
    float* z2     = (float*)wsp; wsp += sizeof(float) * N_GRAPH * HID;
    int*   ideg   = (int*)wsp;   wsp += sizeof(int) * N_NODES;      // fallback only
    size_t core_need = (size_t)(wsp - (char*)d_ws);
    int* blockcnt  = (int*)wsp; wsp += sizeof(int) * NBLK * N_GRAPH;
    int* base2     = (int*)wsp; wsp += sizeof(int) * NBLK * N_GRAPH;
    int* total     = (int*)wsp; wsp += sizeof(int) * N_GRAPH;
    int* gbase     = (int*)wsp; wsp += sizeof(int) * (N_GRAPH + 1);
    int* nodestart = (int*)wsp; wsp += sizeof(int) * (N_GRAPH + 1);
    int2* bin      = (int2*)wsp; wsp += sizeof(int2) * N_EDGES;
    size_t sort_need = (size_t)(wsp - (char*)d_ws);
    unsigned* xbw  = (unsigned*)wsp; wsp += sizeof(unsigned) * XB_WORDS;
    size_t bf_need = (size_t)(wsp - (char*)d_ws);

    if (ws_size >= sort_need) {
        bool bf = ws_size >= bf_need;
        if (bf) pack_kernel<<<(XB_WORDS + 255) / 256, 256, 0, stream>>>(x, xbw);
        hist_kernel<<<NBLK, 256, 0, stream>>>(edst, batch, blockcnt);
        colscan_kernel<<<N_GRAPH, 512, 0, stream>>>(blockcnt, base2, total);
        gscan_kernel<<<1, 512, 0, stream>>>(total, gbase, batch, nodestart, cnt);
        fill_kernel<<<NBLK, 256, 0, stream>>>(esrc, edst, batch, base2, gbase, bin);
        deg_kernel<<<N_GRAPH, 256, 0, stream>>>(bin, gbase, nodestart, dinv);
        if (bf)
            scatter2_kernel<1><<<N_GRAPH * SPLIT, 256, 0, stream>>>(
                x, (const uint2*)xbw, bin, gbase, nodestart, dinv, accp);
        else
            scatter2_kernel<0><<<N_GRAPH * SPLIT, 256, 0, stream>>>(
                x, (const uint2*)xbw, bin, gbase, nodestart, dinv, accp);
        pooled_kernel<SPLIT><<<(N_GRAPH * DOUT + 255) / 256, 256, 0, stream>>>(accp, W, b, cnt, pooled);
    } else if (ws_size >= core_need) {
        init_fb_kernel<<<(N_NODES + 255) / 256, 256, 0, stream>>>(ideg, accp, cnt);
        deg_only_kernel<<<(N_EDGES + 255) / 256, 256, 0, stream>>>(edst, ideg);
        dinv_fb_kernel<<<(N_NODES + 255) / 256, 256, 0, stream>>>(ideg, dinv, batch, cnt);
        scatter_fb_kernel<<<dim3(192, 4), 256, 0, stream>>>(x, ei, batch, dinv, accp);
        pooled_kernel<1><<<(N_GRAPH * DOUT + 255) / 256, 256, 0, stream>>>(accp, W, b, cnt, pooled);
    }

    mlp_kernel<DOUT, HID, true><<<(N_GRAPH * HID + 255) / 256, 256, 0, stream>>>(pooled, W1, b1, z1);
    mlp_kernel<HID,  HID, true><<<(N_GRAPH * HID + 255) / 256, 256, 0, stream>>>(z1, W2, b2, z2);
    head_kernel<<<(N_GRAPH + 255) / 256, 256, 0, stream>>>(z2, Wc, bc, out);
}